// Round 11
// baseline (158.540 us; speedup 1.0000x reference)
//
#include <hip/hip_runtime.h>
#include <hip/hip_bf16.h>

// Retention: out = (tril(alpha^(i-j)) * (QK^T/sqrt(d))) @ V, qkv = x@W + b
// Decay folded into operands: Q' = q*alpha^i/sqrt(d), K' = k*alpha^(-j)
// qkv: 128x192 tile, 6 waves (2Mx3N of 64x64, acc[4][4]), BK=64 dbuf = 80KB LDS
//   (exactly 2 blocks/CU), counted per-role vmcnt gates, r5's proven 0-conflict
//   LDS scheme (128B rows, slot = chunk ^ (row&7), pre-swizzled global source).
//   Model: total time ~ barrier-units/CU x ~1700cyc; this cuts units 108 -> 72
//   and halves per-wave LDS reads/FLOP vs r5's 32x64 waves.
// score/pv: r5 verbatim (proven).

#define SEQ   1024
#define DIM   768
#define ND3   2304

typedef __attribute__((ext_vector_type(8))) short bf16x8;
typedef __attribute__((ext_vector_type(4))) float f32x4;

#define L2A     (-0.014499569695115089f)   // log2(0.99)
#define RSQRTD  (0.03608439182435161f)     // 1/sqrt(768)

__device__ __forceinline__ unsigned short f2bf(float x) {
  union { float f; unsigned u; } v; v.f = x;
  unsigned r = v.u + 0x7FFFu + ((v.u >> 16) & 1u);
  return (unsigned short)(r >> 16);
}

__device__ __forceinline__ void gload16(const void* g, void* l) {
  __builtin_amdgcn_global_load_lds(
      (const __attribute__((address_space(1))) void*)g,
      (__attribute__((address_space(3))) void*)l, 16, 0, 0);
}

// ---------------- prep: convert x f32->bf16 (6144 blocks) + transpose W (432)
__global__ void prep(const float* __restrict__ x, unsigned short* __restrict__ xb,
                     const float* __restrict__ W, unsigned short* __restrict__ Wt) {
  __shared__ float tile[64][65];
  int bid = blockIdx.x;
  if (bid < 6144) {               // convert_x
    size_t i = ((size_t)bid * 256 + threadIdx.x) * 8;
    float4 f0 = *(const float4*)(x + i);
    float4 f1 = *(const float4*)(x + i + 4);
    bf16x8 v;
    v[0] = (short)f2bf(f0.x); v[1] = (short)f2bf(f0.y);
    v[2] = (short)f2bf(f0.z); v[3] = (short)f2bf(f0.w);
    v[4] = (short)f2bf(f1.x); v[5] = (short)f2bf(f1.y);
    v[6] = (short)f2bf(f1.z); v[7] = (short)f2bf(f1.w);
    *(bf16x8*)(xb + i) = v;
  } else {                        // transpose_w
    int tb = bid - 6144;
    int n0 = (tb % 36) * 64;
    int k0 = (tb / 36) * 64;
    int tx = threadIdx.x & 63, ty = threadIdx.x >> 6;
#pragma unroll
    for (int p = 0; p < 16; ++p) {
      int k = ty + p * 4;
      tile[k][tx] = W[(size_t)(k0 + k) * ND3 + n0 + tx];
    }
    __syncthreads();
#pragma unroll
    for (int p = 0; p < 16; ++p) {
      int n = ty + p * 4;
      Wt[(size_t)(n0 + n) * DIM + k0 + tx] = f2bf(tile[tx][n]);
    }
  }
}

// ---------------- QKV: xb[16384][768] @ Wt^T -> Q',K',Vt.
// grid 1536 = 128mt x 12ntb; tile 128x192; 6 waves (2Mx3N of 64x64).
// LDS: A 2x16KB, B 2x24KB (128B rows, slot = chunk ^ (row&7)).
// Staging roles: waves 0-1 stage A (8 gloads each), waves 2-5 stage B (6 each).
__global__ void __launch_bounds__(384, 3) qkv_g(
    const unsigned short* __restrict__ xb, const unsigned short* __restrict__ Wt,
    const float* __restrict__ bias,
    unsigned short* __restrict__ Qs, unsigned short* __restrict__ Ks,
    unsigned short* __restrict__ Vt) {
  __shared__ __align__(1024) char lsA[32768];
  __shared__ __align__(1024) char lsB[49152];
  int bid = (blockIdx.x & 7) * 192 + (blockIdx.x >> 3);   // bijective XCD swizzle
  int mt = bid / 12, ntb = bid % 12;
  int m0 = mt * 128, n0 = ntb * 192;

  int tid = threadIdx.x, lane = tid & 63, wid = tid >> 6;
  int lr = lane & 15, lg = lane >> 4;
  int wm = wid / 3, wn = wid % 3;
  // staging pre-swizzle (per-lane source), r5/r9-proven
  int l8 = lane >> 3, cs = ((lane & 7) ^ l8) << 3;
  // per-role staging source + LDS base
  const unsigned short* gS;
  char* lbase;
  int nld;           // gloads per K-tile for this wave
  if (wid < 2) {     // A rows [wid*64, wid*64+64)
    gS = xb + (size_t)(m0 + wid * 64 + l8) * DIM + cs;
    lbase = lsA + wid * 8192;
    nld = 8;
  } else {           // B rows [(wid-2)*48, +48)
    gS = Wt + (size_t)(n0 + (wid - 2) * 48 + l8) * DIM + cs;
    lbase = lsB + (wid - 2) * 6144;
    nld = 6;
  }
  // read offsets (r5 scheme)
  int rdA = (wm * 64 + lr) * 128 + ((lg ^ (lr & 7)) << 4);   // + f*2048, ^kh<<6
  int rdB = (wn * 64 + lr) * 128 + ((lg ^ (lr & 7)) << 4);   // + n*2048, ^kh<<6

  f32x4 acc[4][4] = {};

#define STG(t, par) do {                                                      \
    char* d_ = lbase + (par) * ((wid < 2) ? 16384 : 24576);                   \
    const unsigned short* s_ = gS + (size_t)(t) * 64;                         \
    _Pragma("unroll")                                                         \
    for (int i_ = 0; i_ < 8; ++i_)                                            \
      if (i_ < nld)                                                           \
        gload16(s_ + (size_t)(i_ * 8) * DIM, d_ + i_ * 1024);                 \
  } while (0)
#define GATE_ROLE do {                                                        \
    if (wid < 2) { asm volatile("s_waitcnt vmcnt(8)" ::: "memory"); }         \
    else         { asm volatile("s_waitcnt vmcnt(6)" ::: "memory"); }         \
  } while (0)

  STG(0, 0);
  STG(1, 1);
  GATE_ROLE;                                 // tile 0 complete per role
  __builtin_amdgcn_s_barrier();
  asm volatile("" ::: "memory");

  for (int t = 0; t < 12; ++t) {
    int pA = (t & 1) * 16384, pB = (t & 1) * 24576;
    bf16x8 aF[2][4], bF[2][4];
#pragma unroll
    for (int kh = 0; kh < 2; ++kh) {
#pragma unroll
      for (int f = 0; f < 4; ++f)
        aF[kh][f] = *(const bf16x8*)(lsA + pA + ((rdA + f * 2048) ^ (kh << 6)));
#pragma unroll
      for (int n = 0; n < 4; ++n)
        bF[kh][n] = *(const bf16x8*)(lsB + pB + ((rdB + n * 2048) ^ (kh << 6)));
    }
    __builtin_amdgcn_s_setprio(1);
#pragma unroll
    for (int kh = 0; kh < 2; ++kh)
#pragma unroll
      for (int f = 0; f < 4; ++f)
#pragma unroll
        for (int n = 0; n < 4; ++n)
          acc[f][n] = __builtin_amdgcn_mfma_f32_16x16x32_bf16(aF[kh][f], bF[kh][n], acc[f][n], 0, 0, 0);
    __builtin_amdgcn_s_setprio(0);

    if (t == 11) break;
    __builtin_amdgcn_s_barrier();            // all reads of this parity done
    asm volatile("" ::: "memory");
    if (t + 2 < 12) {
      STG(t + 2, t & 1);                     // refill buffer tile t used
      GATE_ROLE;                             // tile t+1 ready (counted per role)
    } else {
      asm volatile("s_waitcnt vmcnt(0)" ::: "memory");
    }
    __builtin_amdgcn_s_barrier();
    asm volatile("" ::: "memory");
  }
#undef STG
#undef GATE_ROLE

  float bia[4];
#pragma unroll
  for (int n = 0; n < 4; ++n) bia[n] = bias[n0 + wn * 64 + n * 16 + lr];

  if (ntb < 4) {          // Q: * alpha^s / sqrt(d)
#pragma unroll
    for (int f = 0; f < 4; ++f)
#pragma unroll
      for (int r = 0; r < 4; ++r) {
        int mg = m0 + wm * 64 + f * 16 + lg * 4 + r;
        int b = mg >> 10, s = mg & 1023;
        float sc = exp2f((float)s * L2A) * RSQRTD;
        unsigned short* dst = Qs + ((size_t)b * SEQ + s) * DIM + n0 + wn * 64 + lr;
#pragma unroll
        for (int n = 0; n < 4; ++n)
          dst[n * 16] = f2bf((acc[f][n][r] + bia[n]) * sc);
      }
  } else if (ntb < 8) {   // K: * alpha^(-s)
#pragma unroll
    for (int f = 0; f < 4; ++f)
#pragma unroll
      for (int r = 0; r < 4; ++r) {
        int mg = m0 + wm * 64 + f * 16 + lg * 4 + r;
        int b = mg >> 10, s = mg & 1023;
        float sc = exp2f(-(float)s * L2A);
        unsigned short* dst = Ks + ((size_t)b * SEQ + s) * DIM + (n0 - DIM) + wn * 64 + lr;
#pragma unroll
        for (int n = 0; n < 4; ++n)
          dst[n * 16] = f2bf((acc[f][n][r] + bia[n]) * sc);
      }
  } else {                // V: transpose to Vt[b][d][s]; r runs along s -> 8B stores
#pragma unroll
    for (int f = 0; f < 4; ++f) {
      int mg = m0 + wm * 64 + f * 16 + lg * 4;
      int b = mg >> 10, s0 = mg & 1023;
#pragma unroll
      for (int n = 0; n < 4; ++n) {
        int d = (n0 - 2 * DIM) + wn * 64 + n * 16 + lr;
        ushort4 v;
        v.x = f2bf(acc[f][n][0] + bia[n]);
        v.y = f2bf(acc[f][n][1] + bia[n]);
        v.z = f2bf(acc[f][n][2] + bia[n]);
        v.w = f2bf(acc[f][n][3] + bia[n]);
        *(ushort4*)(Vt + ((size_t)b * DIM + d) * SEQ + s0) = v;
      }
    }
  }
}

// ======================= r5 core (BK=64 dbuf, proven) for score/pv ==========
__device__ __forceinline__ void gemm_core(
    const unsigned short* gA, const unsigned short* gA2,
    const unsigned short* gB, const unsigned short* gB2,
    char* lsA, char* lsB, int nt, int wid, int lane, f32x4 acc[2][4]) {
  int lr = lane & 15, lg = lane >> 4;
  int wm = wid >> 1, wn = wid & 1;
  int rdA = (wm * 32 + lr) * 128 + ((lg ^ (lr & 7)) << 4);
  int rdB = (wn * 64 + lr) * 128 + ((lg ^ (lr & 7)) << 4);
  int wo = wid * 2048;

#define STAGE(t, par) do {                                                    \
    int lo_ = ((par) << 14) + wo;                                             \
    gload16(gA  + (size_t)(t) * 64, lsA + lo_);                               \
    gload16(gA2 + (size_t)(t) * 64, lsA + lo_ + 1024);                        \
    gload16(gB  + (size_t)(t) * 64, lsB + lo_);                               \
    gload16(gB2 + (size_t)(t) * 64, lsB + lo_ + 1024);                        \
  } while (0)

  STAGE(0, 0);
  STAGE(1, 1);
  asm volatile("s_waitcnt vmcnt(4)" ::: "memory");
  __builtin_amdgcn_s_barrier();
  asm volatile("" ::: "memory");

  for (int t = 0; t < nt; ++t) {
    int pbase = (t & 1) << 14;
    bf16x8 aF[2][2], bF[2][4];
#pragma unroll
    for (int kh = 0; kh < 2; ++kh) {
#pragma unroll
      for (int f = 0; f < 2; ++f)
        aF[kh][f] = *(const bf16x8*)(lsA + pbase + ((rdA + f * 2048) ^ (kh << 6)));
#pragma unroll
      for (int n = 0; n < 4; ++n)
        bF[kh][n] = *(const bf16x8*)(lsB + pbase + ((rdB + n * 2048) ^ (kh << 6)));
    }
    __builtin_amdgcn_s_setprio(1);
#pragma unroll
    for (int kh = 0; kh < 2; ++kh)
#pragma unroll
      for (int f = 0; f < 2; ++f)
#pragma unroll
        for (int n = 0; n < 4; ++n)
          acc[f][n] = __builtin_amdgcn_mfma_f32_16x16x32_bf16(aF[kh][f], bF[kh][n], acc[f][n], 0, 0, 0);
    __builtin_amdgcn_s_setprio(0);

    if (t == nt - 1) break;
    __builtin_amdgcn_s_barrier();
    asm volatile("" ::: "memory");
    if (t + 2 < nt) {
      STAGE(t + 2, t & 1);
      asm volatile("s_waitcnt vmcnt(4)" ::: "memory");
    } else {
      asm volatile("s_waitcnt vmcnt(0)" ::: "memory");
    }
    __builtin_amdgcn_s_barrier();
    asm volatile("" ::: "memory");
  }
#undef STAGE
}

// scores: Sm[bl][i][j] = tril(Q' @ K'^T). 36 lower-tri 128x128 tiles/batch
__global__ void __launch_bounds__(512, 4) score_g(
    const unsigned short* __restrict__ Qs, const unsigned short* __restrict__ Ks,
    unsigned short* __restrict__ Sm, int b_base) {
  __shared__ __align__(1024) char lsA[32768];
  __shared__ __align__(1024) char lsB[32768];
  int bid = (blockIdx.x & 7) * (gridDim.x >> 3) + (blockIdx.x >> 3);
  int t = bid % 36, bl = bid / 36;
  int b = b_base + bl;
  int it = 0;
  while (t >= it + 1) { t -= it + 1; it++; }
  int jt = t;
  int m0 = it * 128, n0 = jt * 128;
  const unsigned short* A  = Qs + (size_t)b * SEQ * DIM;
  const unsigned short* Bt = Ks + (size_t)b * SEQ * DIM;
  unsigned short* Smp = Sm + (size_t)bl * SEQ * SEQ;

  int tid = threadIdx.x, lane = tid & 63, wid = tid >> 6;
  int l8 = lane >> 3, cs = ((lane & 7) ^ l8) << 3;
  int srow = wid * 16 + l8;

  const unsigned short* gA = A  + (size_t)(m0 + srow) * DIM + cs;
  const unsigned short* gB = Bt + (size_t)(n0 + srow) * DIM + cs;

  f32x4 acc[2][4] = {};
  gemm_core(gA, gA + 8 * DIM, gB, gB + 8 * DIM, lsA, lsB, 12, wid, lane, acc);

  int wm = wid >> 1, wn = wid & 1;
  int lr = lane & 15, lg = lane >> 4;
#pragma unroll
  for (int f = 0; f < 2; ++f)
#pragma unroll
    for (int n = 0; n < 4; ++n) {
      int j = n0 + wn * 64 + n * 16 + lr;
#pragma unroll
      for (int r = 0; r < 4; ++r) {
        int i = m0 + wm * 32 + f * 16 + lg * 4 + r;
        float v = acc[f][n][r];
        if (j > i) v = 0.0f;   // causal mask (bites only on diagonal tiles)
        Smp[(size_t)i * SEQ + j] = f2bf(v);
      }
    }
}

// PV: out[b][i][d] = Sm[bl] @ V; tiles (i:128, d:128), heavy-first
__global__ void __launch_bounds__(512, 4) pv_g(
    const unsigned short* __restrict__ Sm, const unsigned short* __restrict__ Vt,
    float* __restrict__ out, int b_base, int gsz) {
  __shared__ __align__(1024) char lsA[32768];
  __shared__ __align__(1024) char lsB[32768];
  int it = 7 - blockIdx.x / (gsz * 6);     // heavy (large kmax) first
  int rem = blockIdx.x % (gsz * 6);
  int bl = rem / 6, dt = rem % 6;
  int b = b_base + bl;
  int m0 = it * 128, n0 = dt * 128;
  const unsigned short* A  = Sm + (size_t)bl * SEQ * SEQ;
  const unsigned short* Bt = Vt + (size_t)b * DIM * SEQ;
  int nt = (it + 1) * 2;

  int tid = threadIdx.x, lane = tid & 63, wid = tid >> 6;
  int l8 = lane >> 3, cs = ((lane & 7) ^ l8) << 3;
  int srow = wid * 16 + l8;

  const unsigned short* gA = A  + (size_t)(m0 + srow) * SEQ + cs;
  const unsigned short* gB = Bt + (size_t)(n0 + srow) * SEQ + cs;

  f32x4 acc[2][4] = {};
  gemm_core(gA, gA + 8 * SEQ, gB, gB + 8 * SEQ, lsA, lsB, nt, wid, lane, acc);

  int wm = wid >> 1, wn = wid & 1;
  int lr = lane & 15, lg = lane >> 4;
#pragma unroll
  for (int f = 0; f < 2; ++f)
#pragma unroll
    for (int n = 0; n < 4; ++n) {
      int d = n0 + wn * 64 + n * 16 + lr;
#pragma unroll
      for (int r = 0; r < 4; ++r) {
        int i = m0 + wm * 32 + f * 16 + lg * 4 + r;
        out[((size_t)b * SEQ + i) * DIM + d] = acc[f][n][r];
      }
    }
}

extern "C" void kernel_launch(void* const* d_in, const int* in_sizes, int n_in,
                              void* d_out, int out_size, void* d_ws, size_t ws_size,
                              hipStream_t stream) {
  const float* x    = (const float*)d_in[0];
  const float* W    = (const float*)d_in[1];
  const float* bias = (const float*)d_in[2];
  float* out = (float*)d_out;

  char* ws = (char*)d_ws;
  // ws: Wt 3.5MB | Qs/Ks/Vt 25.2MB each | Sm 16.8MB (8 batches) or 33.6MB (16)
  unsigned short* Wt = (unsigned short*)(ws);
  unsigned short* Qs = (unsigned short*)(ws + 3538944);
  unsigned short* Ks = (unsigned short*)(ws + 3538944 + 25165824);
  unsigned short* Vt = (unsigned short*)(ws + 3538944 + 2 * 25165824);
  unsigned short* Sm = (unsigned short*)(ws + 3538944 + 3 * 25165824);
  // bf16 x lives in d_out (50.3MB >= 25.2MB); fully consumed by qkv before pv writes.
  unsigned short* xb = (unsigned short*)d_out;

  size_t smBase = 3538944 + 3 * (size_t)25165824;
  int gsz = (ws_size >= smBase + (size_t)16 * SEQ * SEQ * 2) ? 16 : 8;
  int ngrp = 16 / gsz;

  prep<<<6576, 256, 0, stream>>>(x, xb, W, Wt);
  qkv_g<<<1536, 384, 0, stream>>>(xb, Wt, bias, Qs, Ks, Vt);
  for (int g = 0; g < ngrp; ++g) {
    score_g<<<gsz * 36, 512, 0, stream>>>(Qs, Ks, Sm, g * gsz);
    pv_g<<<gsz * 48, 512, 0, stream>>>(Sm, Vt, out, g * gsz, gsz);
  }
}

// Round 12
// 138.598 us; speedup vs baseline: 1.1439x; 1.1439x over previous
//
#include <hip/hip_runtime.h>
#include <hip/hip_bf16.h>

// Retention: out = (tril(alpha^(i-j)) * (QK^T/sqrt(d))) @ V, qkv = x@W + b
// Decay folded into operands: Q' = q*alpha^i/sqrt(d), K' = k*alpha^(-j)
// All GEMMs: r5's proven core (128x128 tile, BK=64 dbuf, 8 waves of 32x64,
// counted vmcnt(4) gate, 64KB LDS -> 2 blocks/CU, 0 bank conflicts).
// This round: consolidation. qkv = r5 exact (+ushort4 V store); prep merged;
// pv re-mapped so batch b is processed on XCD b/2 - matching where qkv wrote
// Q/K/Vt(b) and score wrote Sm(b) - so Sm/Vt reads hit the 4MB per-XCD L2.

#define SEQ   1024
#define DIM   768
#define ND3   2304

typedef __attribute__((ext_vector_type(8))) short bf16x8;
typedef __attribute__((ext_vector_type(4))) float f32x4;

#define L2A     (-0.014499569695115089f)   // log2(0.99)
#define RSQRTD  (0.03608439182435161f)     // 1/sqrt(768)

__device__ __forceinline__ unsigned short f2bf(float x) {
  union { float f; unsigned u; } v; v.f = x;
  unsigned r = v.u + 0x7FFFu + ((v.u >> 16) & 1u);
  return (unsigned short)(r >> 16);
}

__device__ __forceinline__ void gload16(const void* g, void* l) {
  __builtin_amdgcn_global_load_lds(
      (const __attribute__((address_space(1))) void*)g,
      (__attribute__((address_space(3))) void*)l, 16, 0, 0);
}

// ======================= r5 core (BK=64 dbuf, proven) =======================
// LDS per operand: 128 lines x 128B (one 64-elem K-row per line);
// line r slot b holds 16B chunk b^(r&7) [0 conflicts, measured r5/r10].
__device__ __forceinline__ void gemm_core(
    const unsigned short* gA, const unsigned short* gA2,
    const unsigned short* gB, const unsigned short* gB2,
    char* lsA, char* lsB, int nt, int wid, int lane, f32x4 acc[2][4]) {
  int lr = lane & 15, lg = lane >> 4;
  int wm = wid >> 1, wn = wid & 1;
  int rdA = (wm * 32 + lr) * 128 + ((lg ^ (lr & 7)) << 4);
  int rdB = (wn * 64 + lr) * 128 + ((lg ^ (lr & 7)) << 4);
  int wo = wid * 2048;

#define STAGE(t, par) do {                                                    \
    int lo_ = ((par) << 14) + wo;                                             \
    gload16(gA  + (size_t)(t) * 64, lsA + lo_);                               \
    gload16(gA2 + (size_t)(t) * 64, lsA + lo_ + 1024);                        \
    gload16(gB  + (size_t)(t) * 64, lsB + lo_);                               \
    gload16(gB2 + (size_t)(t) * 64, lsB + lo_ + 1024);                        \
  } while (0)

  STAGE(0, 0);
  STAGE(1, 1);
  asm volatile("s_waitcnt vmcnt(4)" ::: "memory");   // tile 0 ready
  __builtin_amdgcn_s_barrier();
  asm volatile("" ::: "memory");

  for (int t = 0; t < nt; ++t) {
    int pbase = (t & 1) << 14;
    bf16x8 aF[2][2], bF[2][4];
#pragma unroll
    for (int kh = 0; kh < 2; ++kh) {
#pragma unroll
      for (int f = 0; f < 2; ++f)
        aF[kh][f] = *(const bf16x8*)(lsA + pbase + ((rdA + f * 2048) ^ (kh << 6)));
#pragma unroll
      for (int n = 0; n < 4; ++n)
        bF[kh][n] = *(const bf16x8*)(lsB + pbase + ((rdB + n * 2048) ^ (kh << 6)));
    }
    __builtin_amdgcn_s_setprio(1);
#pragma unroll
    for (int kh = 0; kh < 2; ++kh)
#pragma unroll
      for (int f = 0; f < 2; ++f)
#pragma unroll
        for (int n = 0; n < 4; ++n)
          acc[f][n] = __builtin_amdgcn_mfma_f32_16x16x32_bf16(aF[kh][f], bF[kh][n], acc[f][n], 0, 0, 0);
    __builtin_amdgcn_s_setprio(0);

    if (t == nt - 1) break;
    __builtin_amdgcn_s_barrier();            // all reads of this parity done
    asm volatile("" ::: "memory");
    if (t + 2 < nt) {
      STAGE(t + 2, t & 1);                   // refill buffer tile t used
      asm volatile("s_waitcnt vmcnt(4)" ::: "memory");   // tile t+1 ready
    } else {
      asm volatile("s_waitcnt vmcnt(0)" ::: "memory");
    }
    __builtin_amdgcn_s_barrier();
    asm volatile("" ::: "memory");
  }
#undef STAGE
}

// ---------------- prep: convert x f32->bf16 (6144 blocks) + transpose W (432)
__global__ void prep(const float* __restrict__ x, unsigned short* __restrict__ xb,
                     const float* __restrict__ W, unsigned short* __restrict__ Wt) {
  __shared__ float tile[64][65];
  int bid = blockIdx.x;
  if (bid < 6144) {               // convert_x
    size_t i = ((size_t)bid * 256 + threadIdx.x) * 8;
    float4 f0 = *(const float4*)(x + i);
    float4 f1 = *(const float4*)(x + i + 4);
    bf16x8 v;
    v[0] = (short)f2bf(f0.x); v[1] = (short)f2bf(f0.y);
    v[2] = (short)f2bf(f0.z); v[3] = (short)f2bf(f0.w);
    v[4] = (short)f2bf(f1.x); v[5] = (short)f2bf(f1.y);
    v[6] = (short)f2bf(f1.z); v[7] = (short)f2bf(f1.w);
    *(bf16x8*)(xb + i) = v;
  } else {                        // transpose_w
    int tb = bid - 6144;
    int n0 = (tb % 36) * 64;
    int k0 = (tb / 36) * 64;
    int tx = threadIdx.x & 63, ty = threadIdx.x >> 6;
#pragma unroll
    for (int p = 0; p < 16; ++p) {
      int k = ty + p * 4;
      tile[k][tx] = W[(size_t)(k0 + k) * ND3 + n0 + tx];
    }
    __syncthreads();
#pragma unroll
    for (int p = 0; p < 16; ++p) {
      int n = ty + p * 4;
      Wt[(size_t)(n0 + n) * DIM + k0 + tx] = f2bf(tile[tx][n]);
    }
  }
}

// ---------------- QKV: xb[16384][768] @ Wt^T -> Q',K',Vt. grid 2304 = 128mt x 18nt
// (r5 exact; XCD chunking gives mt in [16x, 16x+16) on XCD x -> batches 2x,2x+1)
__global__ void __launch_bounds__(512, 4) qkv_g(
    const unsigned short* __restrict__ xb, const unsigned short* __restrict__ Wt,
    const float* __restrict__ bias,
    unsigned short* __restrict__ Qs, unsigned short* __restrict__ Ks,
    unsigned short* __restrict__ Vt) {
  __shared__ __align__(1024) char lsA[32768];
  __shared__ __align__(1024) char lsB[32768];
  int bid = (blockIdx.x & 7) * 288 + (blockIdx.x >> 3);   // bijective XCD swizzle
  int mt = bid / 18, ntb = bid % 18;
  int m0 = mt * 128, n0 = ntb * 128;

  int tid = threadIdx.x, lane = tid & 63, wid = tid >> 6;
  int l8 = lane >> 3, cs = ((lane & 7) ^ l8) << 3;        // pre-swizzled chunk col
  int srow = wid * 16 + l8;

  const unsigned short* gA = xb + (size_t)(m0 + srow) * DIM + cs;
  const unsigned short* gB = Wt + (size_t)(n0 + srow) * DIM + cs;

  f32x4 acc[2][4] = {};
  gemm_core(gA, gA + 8 * DIM, gB, gB + 8 * DIM, lsA, lsB, 12, wid, lane, acc);

  int wm = wid >> 1, wn = wid & 1;
  int lr = lane & 15, lg = lane >> 4;
  float bia[4];
#pragma unroll
  for (int n = 0; n < 4; ++n) bia[n] = bias[n0 + wn * 64 + n * 16 + lr];

  if (ntb < 6) {           // Q: * alpha^s / sqrt(d)
#pragma unroll
    for (int f = 0; f < 2; ++f)
#pragma unroll
      for (int r = 0; r < 4; ++r) {
        int mg = m0 + wm * 32 + f * 16 + lg * 4 + r;
        int b = mg >> 10, s = mg & 1023;
        float sc = exp2f((float)s * L2A) * RSQRTD;
        unsigned short* dst = Qs + ((size_t)b * SEQ + s) * DIM + n0 + wn * 64 + lr;
#pragma unroll
        for (int n = 0; n < 4; ++n)
          dst[n * 16] = f2bf((acc[f][n][r] + bia[n]) * sc);
      }
  } else if (ntb < 12) {   // K: * alpha^(-s)
#pragma unroll
    for (int f = 0; f < 2; ++f)
#pragma unroll
      for (int r = 0; r < 4; ++r) {
        int mg = m0 + wm * 32 + f * 16 + lg * 4 + r;
        int b = mg >> 10, s = mg & 1023;
        float sc = exp2f(-(float)s * L2A);
        unsigned short* dst = Ks + ((size_t)b * SEQ + s) * DIM + (n0 - DIM) + wn * 64 + lr;
#pragma unroll
        for (int n = 0; n < 4; ++n)
          dst[n * 16] = f2bf((acc[f][n][r] + bia[n]) * sc);
      }
  } else {                 // V: transpose to Vt[b][d][s]; r runs along s -> 8B stores
#pragma unroll
    for (int f = 0; f < 2; ++f) {
      int mg = m0 + wm * 32 + f * 16 + lg * 4;
      int b = mg >> 10, s0 = mg & 1023;
#pragma unroll
      for (int n = 0; n < 4; ++n) {
        int d = (n0 - 2 * DIM) + wn * 64 + n * 16 + lr;
        ushort4 v;
        v.x = f2bf(acc[f][n][0] + bia[n]);
        v.y = f2bf(acc[f][n][1] + bia[n]);
        v.z = f2bf(acc[f][n][2] + bia[n]);
        v.w = f2bf(acc[f][n][3] + bia[n]);
        *(ushort4*)(Vt + ((size_t)b * DIM + d) * SEQ + s0) = v;
      }
    }
  }
}

// ---------------- scores: Sm[bl][i][j] = tril(Q' @ K'^T). 36 tril 128^2 tiles/batch
// (XCD chunking: XCD x handles bids [x*gsz*36/8, ...) -> batches pinned per XCD)
__global__ void __launch_bounds__(512, 4) score_g(
    const unsigned short* __restrict__ Qs, const unsigned short* __restrict__ Ks,
    unsigned short* __restrict__ Sm, int b_base) {
  __shared__ __align__(1024) char lsA[32768];
  __shared__ __align__(1024) char lsB[32768];
  int bid = (blockIdx.x & 7) * (gridDim.x >> 3) + (blockIdx.x >> 3);
  int t = bid % 36, bl = bid / 36;
  int b = b_base + bl;
  int it = 0;
  while (t >= it + 1) { t -= it + 1; it++; }
  int jt = t;
  int m0 = it * 128, n0 = jt * 128;
  const unsigned short* A  = Qs + (size_t)b * SEQ * DIM;
  const unsigned short* Bt = Ks + (size_t)b * SEQ * DIM;
  unsigned short* Smp = Sm + (size_t)bl * SEQ * SEQ;

  int tid = threadIdx.x, lane = tid & 63, wid = tid >> 6;
  int l8 = lane >> 3, cs = ((lane & 7) ^ l8) << 3;
  int srow = wid * 16 + l8;

  const unsigned short* gA = A  + (size_t)(m0 + srow) * DIM + cs;
  const unsigned short* gB = Bt + (size_t)(n0 + srow) * DIM + cs;

  f32x4 acc[2][4] = {};
  gemm_core(gA, gA + 8 * DIM, gB, gB + 8 * DIM, lsA, lsB, 12, wid, lane, acc);

  int wm = wid >> 1, wn = wid & 1;
  int lr = lane & 15, lg = lane >> 4;
#pragma unroll
  for (int f = 0; f < 2; ++f)
#pragma unroll
    for (int n = 0; n < 4; ++n) {
      int j = n0 + wn * 64 + n * 16 + lr;
#pragma unroll
      for (int r = 0; r < 4; ++r) {
        int i = m0 + wm * 32 + f * 16 + lg * 4 + r;
        float v = acc[f][n][r];
        if (j > i) v = 0.0f;   // causal mask (bites only on diagonal tiles)
        Smp[(size_t)i * SEQ + j] = f2bf(v);
      }
    }
}

// ---------------- PV: out[b][i][d] = Sm[bl] @ V; batch->XCD pinned, heavy-first
// XCD x owns batches [x*(gsz/8), (x+1)*(gsz/8)); within an XCD, it descends.
// Sm(b) (2MB) and Vt(b) (1.6MB) were written on the same XCD -> L2 hits.
__global__ void __launch_bounds__(512, 4) pv_g(
    const unsigned short* __restrict__ Sm, const unsigned short* __restrict__ Vt,
    float* __restrict__ out, int b_base, int gsz) {
  __shared__ __align__(1024) char lsA[32768];
  __shared__ __align__(1024) char lsB[32768];
  int xcd = blockIdx.x & 7;
  int j = blockIdx.x >> 3;          // [0, gsz*6)
  int nbx = gsz >> 3;               // batches per XCD (1 or 2)
  int perit = nbx * 6;
  int it = 7 - j / perit;           // heavy (large kmax) first within XCD
  int rem = j % perit;
  int bl = xcd * nbx + rem / 6;
  int dt = rem % 6;
  int b = b_base + bl;
  int m0 = it * 128, n0 = dt * 128;
  const unsigned short* A  = Sm + (size_t)bl * SEQ * SEQ;   // ld 1024
  const unsigned short* Bt = Vt + (size_t)b * DIM * SEQ;    // ld 1024
  int nt = (it + 1) * 2;            // K-tiles of 64, causal bound

  int tid = threadIdx.x, lane = tid & 63, wid = tid >> 6;
  int l8 = lane >> 3, cs = ((lane & 7) ^ l8) << 3;
  int srow = wid * 16 + l8;

  const unsigned short* gA = A  + (size_t)(m0 + srow) * SEQ + cs;
  const unsigned short* gB = Bt + (size_t)(n0 + srow) * SEQ + cs;

  f32x4 acc[2][4] = {};
  gemm_core(gA, gA + 8 * SEQ, gB, gB + 8 * SEQ, lsA, lsB, nt, wid, lane, acc);

  int wm = wid >> 1, wn = wid & 1;
  int lr = lane & 15, lg = lane >> 4;
#pragma unroll
  for (int f = 0; f < 2; ++f)
#pragma unroll
    for (int n = 0; n < 4; ++n) {
      int d = n0 + wn * 64 + n * 16 + lr;
#pragma unroll
      for (int r = 0; r < 4; ++r) {
        int i = m0 + wm * 32 + f * 16 + lg * 4 + r;
        out[((size_t)b * SEQ + i) * DIM + d] = acc[f][n][r];
      }
    }
}

extern "C" void kernel_launch(void* const* d_in, const int* in_sizes, int n_in,
                              void* d_out, int out_size, void* d_ws, size_t ws_size,
                              hipStream_t stream) {
  const float* x    = (const float*)d_in[0];
  const float* W    = (const float*)d_in[1];
  const float* bias = (const float*)d_in[2];
  float* out = (float*)d_out;

  char* ws = (char*)d_ws;
  // ws: Wt 3.5MB | Qs/Ks/Vt 25.2MB each | Sm 16.8MB (8 batches) or 33.6MB (16)
  unsigned short* Wt = (unsigned short*)(ws);
  unsigned short* Qs = (unsigned short*)(ws + 3538944);
  unsigned short* Ks = (unsigned short*)(ws + 3538944 + 25165824);
  unsigned short* Vt = (unsigned short*)(ws + 3538944 + 2 * 25165824);
  unsigned short* Sm = (unsigned short*)(ws + 3538944 + 3 * 25165824);
  // bf16 x lives in d_out (50.3MB >= 25.2MB); fully consumed by qkv before pv writes.
  unsigned short* xb = (unsigned short*)d_out;

  size_t smBase = 3538944 + 3 * (size_t)25165824;
  int gsz = (ws_size >= smBase + (size_t)16 * SEQ * SEQ * 2) ? 16 : 8;
  int ngrp = 16 / gsz;

  prep<<<6576, 256, 0, stream>>>(x, xb, W, Wt);
  qkv_g<<<2304, 512, 0, stream>>>(xb, Wt, bias, Qs, Ks, Vt);
  for (int g = 0; g < ngrp; ++g) {
    score_g<<<gsz * 36, 512, 0, stream>>>(Qs, Ks, Sm, g * gsz);
    pv_g<<<gsz * 48, 512, 0, stream>>>(Sm, Vt, out, g * gsz, gsz);
  }
}